// Round 15
// baseline (62.716 us; speedup 1.0000x reference)
//
#include <hip/hip_runtime.h>
#include <cstdint>
#include <cstddef>

typedef unsigned short u16;
typedef unsigned int u32;
typedef __bf16 bf16x8 __attribute__((ext_vector_type(8)));
typedef float f32x4 __attribute__((ext_vector_type(4)));
typedef float f32x2 __attribute__((ext_vector_type(2)));
typedef u32 u32x4 __attribute__((ext_vector_type(4)));

#define M_TOT 16384
#define C_TOT 1000        // classes
#define N_PAD 1024        // padded Wdiff rows
#define K_TOT 512
#define OUT_STRIDE 2000   // out row stride in floats
#define NT 16             // K-steps of 32
#define NWG 2048          // (16384/32) m-tiles * 4 n-panels

// ---------- f32 -> bf16 (RNE) ----------
__device__ __forceinline__ u16 f2bf(float f) {
  u32 u = __float_as_uint(f);
  u = (u + 0x7FFFu + ((u >> 16) & 1u)) >> 16;
  return (u16)u;
}

__device__ __forceinline__ u32 cvtpk(float lo, float hi) {
  u32 d;
  asm("v_cvt_pk_bf16_f32 %0, %1, %2" : "=v"(d) : "v"(lo), "v"(hi));
  return d;
}

// W prep -> FRAG-MAJOR Wdiff: for MFMA B-frag (nf, kt) the 1KB block at
// ((nf*16)+kt)*1024 B holds lane-ordered data: lane = (n&15) | (((k>>3)&3)<<4),
// elems k&7. A B-frag load is then one fully-coalesced 1KB wave read.
// Rows >= C_TOT zero-padded. bdiff[c] = b[2c]-b[2c+1].
__global__ __launch_bounds__(256) void wprep_kernel(const float* __restrict__ W,
                                                    const float* __restrict__ b,
                                                    u16* __restrict__ wd,
                                                    float* __restrict__ bd) {
  const int i = blockIdx.x * 256 + threadIdx.x;  // 65536 threads
  const int c = i >> 6;        // n-row 0..1023
  const int seg = i & 63;      // 8-elem k granule (k0 = seg*8)
  ushort4 r0 = {0, 0, 0, 0}, r1 = {0, 0, 0, 0};
  if (c < C_TOT) {
    const float4* w0 = (const float4*)(W + (size_t)(2 * c) * K_TOT) + seg * 2;
    const float4* w1 = (const float4*)(W + (size_t)(2 * c + 1) * K_TOT) + seg * 2;
    float4 a0 = w0[0], a1 = w0[1], c0 = w1[0], c1 = w1[1];
    r0.x = f2bf(a0.x - c0.x); r0.y = f2bf(a0.y - c0.y);
    r0.z = f2bf(a0.z - c0.z); r0.w = f2bf(a0.w - c0.w);
    r1.x = f2bf(a1.x - c1.x); r1.y = f2bf(a1.y - c1.y);
    r1.z = f2bf(a1.z - c1.z); r1.w = f2bf(a1.w - c1.w);
    if (seg == 0) bd[c] = b[2 * c] - b[2 * c + 1];
  } else if (seg == 0) {
    bd[c] = 0.0f;
  }
  // frag-major dest: block ((c>>4)*16 + (seg>>2)), lane (c&15)+(seg&3)*16
  const size_t idx = ((size_t)(c >> 4) * 16 + (seg >> 2)) * 512 +
                     ((size_t)(c & 15) + (seg & 3) * 16) * 8;
  *(ushort4*)(wd + idx) = r0;
  *(ushort4*)(wd + idx + 4) = r1;
}

// ---------- GEMM (M=16384, N=1024pad, K=512) + fused x-cvt + pairwise log_softmax ----------
// BARRIER-FREE design (R15). Block = 32 m-rows x 256 n-cols, 4 waves.
//  - A-panel (32x512 bf16, 32KB) staged ONCE (f32->cvt_pk->swizzled LDS), one
//    __syncthreads; read-only afterwards.
//  - B is 1MB and L2-resident (lesson #7: don't LDS-stage what L2-fits): each
//    wave loads its 4 B-frags per K-step DIRECTLY from global (frag-major
//    layout -> one coalesced 1KB read per frag). No barriers, no vmcnt pinning:
//    16 independent waves/CU hide latency; stores self-spread in time.
// A LDS swizzle: logical (row, slot s) stored at s' = s ^ (row&7); frag read
// quarter-wave = 16 rows x same s-base -> 8 distinct bank-quads x 2 = free
// (model calibrated on R8/R13/R14 conflict counters).
__global__ __launch_bounds__(256, 4) void gemm_ls_kernel(const float* __restrict__ Af,
                                                         const u16* __restrict__ B2,
                                                         const float* __restrict__ bdiff,
                                                         float* __restrict__ out) {
  __shared__ u16 Alds[32 * 512];  // 32 KB -> 4 blocks/CU (16 waves)

  const int tid = threadIdx.x;
  const int lane = tid & 63;
  const int w = tid >> 6;          // wave 0..3
  const int lrow = lane & 15;
  const int lhi = lane >> 4;

  // XCD-chunked swizzle (NWG=2048, 256/XCD, bijective)
  const int bid = blockIdx.x;
  const int wg = (bid & 7) * (NWG / 8) + (bid >> 3);
  const int m0 = (wg >> 2) * 32;           // 512 m-tiles
  const int n0w = (wg & 3) * 256 + w * 64; // this wave's 64 n-cols
  const int nf0 = n0w >> 4;                // first of its 4 n-frags

  // per-frag bias + column (guard only needed when n0w == 960)
  float bd[4];
  int ncol[4];
#pragma unroll
  for (int f = 0; f < 4; ++f) {
    ncol[f] = n0w + f * 16 + lrow;
    bd[f] = bdiff[ncol[f]];
  }

  // prefetch B k-step 0 (flies under A staging)
  bf16x8 bfr[2][4];
#pragma unroll
  for (int f = 0; f < 4; ++f)
    bfr[0][f] = *(const bf16x8*)(B2 + ((size_t)(nf0 + f) * 16 + 0) * 512 + lane * 8);

  // ---- stage A panel: 32 rows x 512 k, f32 -> bf16, swizzled ----
#pragma unroll
  for (int i = 0; i < 8; ++i) {
    const int G = i * 256 + tid;           // physical granule 0..2047
    const int row = G >> 6, slot = G & 63;
    const int g = slot ^ (row & 7);        // source k-granule (XOR involution)
    const f32x4* src = (const f32x4*)(Af + (size_t)(m0 + row) * K_TOT + g * 8);
    f32x4 a = src[0], c = src[1];
    u32x4 wv;
    wv.x = cvtpk(a.x, a.y);
    wv.y = cvtpk(a.z, a.w);
    wv.z = cvtpk(c.x, c.y);
    wv.w = cvtpk(c.z, c.w);
    *(u32x4*)(&Alds[(size_t)row * 512 + slot * 8]) = wv;
  }
  __syncthreads();  // the ONLY barrier

  f32x4 acc[2][4] = {};
  const int abase0 = lrow * 1024;          // byte base, m-frag 0 (rows 0-15)
  const int abase1 = (16 + lrow) * 1024;   // m-frag 1 (rows 16-31)
  const int akey = lrow & 7;

#define STEPK(T)                                                               \
  do {                                                                         \
    if ((T) < NT - 1) {                                                        \
      _Pragma("unroll") for (int f = 0; f < 4; ++f)                            \
          bfr[((T) + 1) & 1][f] = *(const bf16x8*)(                            \
              B2 + ((size_t)(nf0 + f) * 16 + (T) + 1) * 512 + lane * 8);       \
    }                                                                          \
    const int s0 = (((((T) << 2) | lhi)) ^ akey) << 4;                         \
    bf16x8 a0 = *(const bf16x8*)((const char*)Alds + abase0 + s0);             \
    bf16x8 a1 = *(const bf16x8*)((const char*)Alds + abase1 + s0);             \
    _Pragma("unroll") for (int f = 0; f < 4; ++f) {                            \
      acc[0][f] = __builtin_amdgcn_mfma_f32_16x16x32_bf16(a0, bfr[(T) & 1][f], \
                                                          acc[0][f], 0, 0, 0); \
      acc[1][f] = __builtin_amdgcn_mfma_f32_16x16x32_bf16(a1, bfr[(T) & 1][f], \
                                                          acc[1][f], 0, 0, 0); \
    }                                                                          \
  } while (0)

  STEPK(0);  STEPK(1);  STEPK(2);  STEPK(3);
  STEPK(4);  STEPK(5);  STEPK(6);  STEPK(7);
  STEPK(8);  STEPK(9);  STEPK(10); STEPK(11);
  STEPK(12); STEPK(13); STEPK(14); STEPK(15);
#undef STEPK

  // ---- epilogue: d -> (o0, o1) f32x2 store; waves store independently ----
#pragma unroll
  for (int f = 0; f < 4; ++f) {
    if (ncol[f] < C_TOT) {
      const float bd_r = bd[f];
#pragma unroll
      for (int mf = 0; mf < 2; ++mf) {
#pragma unroll
        for (int j = 0; j < 4; ++j) {
          const float d = acc[mf][f][j] + bd_r;
          const float o0 = fminf(d, 0.0f) - __logf(1.0f + __expf(-fabsf(d)));
          const int row = m0 + mf * 16 + lhi * 4 + j;
          f32x2 v;
          v.x = o0;
          v.y = o0 - d;
          *(f32x2*)(out + (size_t)row * OUT_STRIDE + 2 * ncol[f]) = v;
        }
      }
    }
  }
}

// ---------- naive fp32 fallback (only if ws too small) ----------
__global__ __launch_bounds__(256) void naive_kernel(const float* __restrict__ x,
                                                    const float* __restrict__ W,
                                                    const float* __restrict__ b,
                                                    float* __restrict__ out) {
  __shared__ float xs[K_TOT];
  const int row = blockIdx.x;
  for (int i = threadIdx.x; i < K_TOT; i += 256) xs[i] = x[(size_t)row * K_TOT + i];
  __syncthreads();
  for (int c = threadIdx.x; c < C_TOT; c += 256) {
    const float* w0 = W + (size_t)c * 1024;
    float l0 = b[c * 2], l1 = b[c * 2 + 1];
    for (int k = 0; k < K_TOT; ++k) {
      const float xv = xs[k];
      l0 += xv * w0[k];
      l1 += xv * w0[K_TOT + k];
    }
    const float d = l0 - l1;
    const float t = __logf(1.0f + __expf(-fabsf(d)));
    out[(size_t)row * OUT_STRIDE + c * 2]     = fminf(d, 0.0f) - t;
    out[(size_t)row * OUT_STRIDE + c * 2 + 1] = fminf(-d, 0.0f) - t;
  }
}

extern "C" void kernel_launch(void* const* d_in, const int* in_sizes, int n_in,
                              void* d_out, int out_size, void* d_ws, size_t ws_size,
                              hipStream_t stream) {
  const float* x = (const float*)d_in[0];   // [16384, 512]
  const float* W = (const float*)d_in[1];   // [1000, 2, 512]
  const float* b = (const float*)d_in[2];   // [1000, 2]
  float* out = (float*)d_out;               // [16384, 1000, 2]

  const size_t nwd = (size_t)N_PAD * K_TOT;                 // 524288 elems
  const size_t need = nwd * sizeof(u16) + N_PAD * sizeof(float);

  if (ws_size < need) {
    naive_kernel<<<M_TOT, 256, 0, stream>>>(x, W, b, out);
    return;
  }

  u16* wd = (u16*)d_ws;
  float* bd = (float*)(wd + nwd);

  wprep_kernel<<<256, 256, 0, stream>>>(W, b, wd, bd);
  gemm_ls_kernel<<<NWG, 256, 0, stream>>>(x, wd, bd, out);
}

// Round 16
// 48.358 us; speedup vs baseline: 1.2969x; 1.2969x over previous
//
#include <hip/hip_runtime.h>
#include <cstdint>
#include <cstddef>

typedef unsigned short u16;
typedef unsigned int u32;
typedef __bf16 bf16x8 __attribute__((ext_vector_type(8)));
typedef float f32x4 __attribute__((ext_vector_type(4)));
typedef float f32x2 __attribute__((ext_vector_type(2)));
typedef u32 u32x4 __attribute__((ext_vector_type(4)));

#define M_TOT 16384
#define C_TOT 1000        // classes = GEMM N dimension
#define N_PAD 1024        // padded B rows
#define K_TOT 512
#define OUT_STRIDE 2000   // out row stride in floats
#define BM 128
#define BN 128
#define BK 32
#define NT 16             // K-tiles: 512/32
#define NWG 1024          // (16384/128) * (1024/128)

// ---------- f32 -> bf16 (RNE) ----------
__device__ __forceinline__ u16 f2bf(float f) {
  u32 u = __float_as_uint(f);
  u = (u + 0x7FFFu + ((u >> 16) & 1u)) >> 16;
  return (u16)u;
}

// packed RNE cvt: dst = bf16(lo) | bf16(hi)<<16
__device__ __forceinline__ u32 cvtpk(float lo, float hi) {
  u32 d;
  asm("v_cvt_pk_bf16_f32 %0, %1, %2" : "=v"(d) : "v"(lo), "v"(hi));
  return d;
}

// W prep: Wdiff[c,:] = bf16(W[c,0,:]-W[c,1,:]) zero-padded to 1024 rows; bdiff
__global__ __launch_bounds__(256) void wprep_kernel(const float* __restrict__ W,
                                                    const float* __restrict__ b,
                                                    u16* __restrict__ wd,
                                                    float* __restrict__ bd) {
  const int i = blockIdx.x * 256 + threadIdx.x;  // 65536 threads
  const int c = i >> 6;        // row 0..1023
  const int seg = i & 63;      // 8-elem segment of the 512-wide row
  ushort4 r0 = {0, 0, 0, 0}, r1 = {0, 0, 0, 0};
  if (c < C_TOT) {
    const float4* w0 = (const float4*)(W + (size_t)(2 * c) * K_TOT) + seg * 2;
    const float4* w1 = (const float4*)(W + (size_t)(2 * c + 1) * K_TOT) + seg * 2;
    float4 a0 = w0[0], a1 = w0[1], c0 = w1[0], c1 = w1[1];
    r0.x = f2bf(a0.x - c0.x); r0.y = f2bf(a0.y - c0.y);
    r0.z = f2bf(a0.z - c0.z); r0.w = f2bf(a0.w - c0.w);
    r1.x = f2bf(a1.x - c1.x); r1.y = f2bf(a1.y - c1.y);
    r1.z = f2bf(a1.z - c1.z); r1.w = f2bf(a1.w - c1.w);
    if (seg == 0) bd[c] = b[2 * c] - b[2 * c + 1];
  } else if (seg == 0) {
    bd[c] = 0.0f;
  }
  ushort4* d = (ushort4*)(wd + (size_t)c * K_TOT);
  d[seg * 2] = r0;
  d[seg * 2 + 1] = r1;
}

// ---------- async global -> LDS, 16B per lane ----------
__device__ __forceinline__ void gload_lds(const u16* g, u16* l) {
  __builtin_amdgcn_global_load_lds((const __attribute__((address_space(1))) u32*)g,
                                   (__attribute__((address_space(3))) u32*)l, 16, 0, 0);
}

// Stage one 8KB bf16 tile (128 rows x 32, stride K_TOT) into swizzled LDS.
// granule(r,q) -> lrow=r&63, pos=(((r>>6)<<2)|q)^(r&7), byte=lrow*128+pos*16.
__device__ __forceinline__ void stage8k(const u16* __restrict__ gbase,
                                        u16* lb, int tid) {
#pragma unroll
  for (int i = 0; i < 2; ++i) {
    const int g = i * 256 + tid;          // dest granule 0..511
    const int lrow = g >> 3;
    const int u = (g & 7) ^ (lrow & 7);   // inverse swizzle
    const int r = lrow | ((u >> 2) << 6);
    const int q = u & 3;
    gload_lds(gbase + (size_t)r * K_TOT + q * 8, lb + (size_t)g * 8);
  }
}

#define VMW(N) asm volatile("s_waitcnt vmcnt(" #N ")" ::: "memory")
#define CFENCE asm volatile("" ::: "memory")

// ---------- GEMM (M=16384, N=1024pad, K=512) + fused x-cvt + pairwise log_softmax ----------
// R9 EXACT RESTORE (session best: 48.9us). A: x f32 -> reg (depth-2) ->
// cvt_pk bf16 -> ds_write swizzled As[2] (published in-step). B: Wdiff bf16
// via gload_lds, Bs[3], depth-2. LDS 40KB -> 4 blocks/CU (16 waves/CU).
// Ledger: prologue A0(4),B0(1x2),B1(1x2)=8; steady VMW(2) retires {A(T),B(T)};
// issue A(T+1)[4] + B(T+2)[2] per step. Verified vs R8(50.9)/R10(52.3)/
// R12(53.6)/R13-14(52.x)/R15(62.7): bottom of this structure's basin.
__global__ __launch_bounds__(256, 4) void gemm_ls_kernel(const float* __restrict__ Af,
                                                         const u16* __restrict__ B,
                                                         const float* __restrict__ bdiff,
                                                         float* __restrict__ out) {
  __shared__ u16 As[2][4096];  // 16 KB
  __shared__ u16 Bs[3][4096];  // 24 KB -> 40 KB total

  const int tid = threadIdx.x;
  const int lane = tid & 63;
  const int w = tid >> 6;
  const int wm = w >> 1;
  const int wn = w & 1;

  // XCD-chunked swizzle (NWG=1024, 128 blocks/XCD, bijective)
  const int bid = blockIdx.x;
  const int wg = (bid & 7) * (NWG / 8) + (bid >> 3);
  const int m0 = (wg >> 3) * BM;
  const int n0 = (wg & 7) * BN;

  const float* gAf = Af + (size_t)m0 * K_TOT;
  const u16* gB = B + (size_t)n0 * K_TOT;   // padded rows: unguarded

  // A staging source (inverse-swizzled f32 granules for dest g = tid, 256+tid)
  const int lrow0 = tid >> 3;
  const int au = (tid & 7) ^ (lrow0 & 7);
  const int qA = au & 3;
  const int rA0 = lrow0 | ((au >> 2) << 6);
  const int rA1 = (32 + lrow0) | ((au >> 2) << 6);
  const f32x4* gq0 = (const f32x4*)gAf + (size_t)rA0 * 128 + qA * 2;
  const f32x4* gq1 = (const f32x4*)gAf + (size_t)rA1 * 128 + qA * 2;

  // per-lane swizzled LDS byte offsets for the 4 A-frags / 4 B-frags
  const int ar = lane & 15;
  const int kq4 = lane >> 4;
  int offA[4], offB[4];
#pragma unroll
  for (int i = 0; i < 4; ++i) {
    int r = wm * 64 + i * 16 + ar;
    offA[i] = (r & 63) * 128 + (((((r >> 6) << 2) | kq4) ^ (r & 7)) << 4);
    r = wn * 64 + i * 16 + ar;
    offB[i] = (r & 63) * 128 + (((((r >> 6) << 2) | kq4) ^ (r & 7)) << 4);
  }

  f32x4 acc[4][4] = {};
  f32x4 areg[2][4];  // depth-2 A reg rotation, statically indexed (full unroll)

#define ALOAD(T)                                   \
  do {                                             \
    areg[(T) & 1][0] = gq0[(T) * 8];               \
    areg[(T) & 1][1] = gq0[(T) * 8 + 1];           \
    areg[(T) & 1][2] = gq1[(T) * 8];               \
    areg[(T) & 1][3] = gq1[(T) * 8 + 1];           \
  } while (0)

#define ACVT_WR(T)                                                        \
  do {                                                                    \
    u32x4 w0, w1;                                                         \
    w0.x = cvtpk(areg[(T) & 1][0].x, areg[(T) & 1][0].y);                 \
    w0.y = cvtpk(areg[(T) & 1][0].z, areg[(T) & 1][0].w);                 \
    w0.z = cvtpk(areg[(T) & 1][1].x, areg[(T) & 1][1].y);                 \
    w0.w = cvtpk(areg[(T) & 1][1].z, areg[(T) & 1][1].w);                 \
    w1.x = cvtpk(areg[(T) & 1][2].x, areg[(T) & 1][2].y);                 \
    w1.y = cvtpk(areg[(T) & 1][2].z, areg[(T) & 1][2].w);                 \
    w1.z = cvtpk(areg[(T) & 1][3].x, areg[(T) & 1][3].y);                 \
    w1.w = cvtpk(areg[(T) & 1][3].z, areg[(T) & 1][3].w);                 \
    *(u32x4*)(&As[(T) & 1][(size_t)tid * 8]) = w0;                        \
    *(u32x4*)(&As[(T) & 1][(size_t)(256 + tid) * 8]) = w1;                \
  } while (0)

#define BSTAGE(T) stage8k(gB + (T) * BK, &Bs[(T) % 3][0], tid)

#define COMPUTE(T)                                                          \
  do {                                                                      \
    bf16x8 af[4], bf[4];                                                    \
    _Pragma("unroll") for (int i = 0; i < 4; ++i)                           \
        af[i] = *(const bf16x8*)((const char*)&As[(T) & 1][0] + offA[i]);   \
    _Pragma("unroll") for (int i = 0; i < 4; ++i)                           \
        bf[i] = *(const bf16x8*)((const char*)&Bs[(T) % 3][0] + offB[i]);   \
    _Pragma("unroll") for (int mi = 0; mi < 4; ++mi)                        \
        _Pragma("unroll") for (int ni = 0; ni < 4; ++ni)                    \
            acc[mi][ni] = __builtin_amdgcn_mfma_f32_16x16x32_bf16(          \
                af[mi], bf[ni], acc[mi][ni], 0, 0, 0);                      \
  } while (0)

// per K-step. vmcnt ledger (sim'd): prologue A0|B0|B1 = 8 outstanding;
// steady: wait(2) retires {A(T),B(T)}; issue A(T+1) [4] + B(T+2) [2].
#define STEP(T, VMN)                                         \
  do {                                                       \
    VMW(VMN);                                                \
    CFENCE;                                                  \
    ACVT_WR(T);                                              \
    if ((T) + 1 < NT) ALOAD((T) + 1);                        \
    asm volatile("s_waitcnt lgkmcnt(0)" ::: "memory");       \
    __builtin_amdgcn_s_barrier();                            \
    CFENCE;                                                  \
    if ((T) + 2 < NT) BSTAGE((T) + 2);                       \
    __builtin_amdgcn_s_setprio(1);                           \
    COMPUTE(T);                                              \
    __builtin_amdgcn_s_setprio(0);                           \
  } while (0)

  // prologue: A0 regs, B0/B1 LDS in flight (issue order matters for vmcnt)
  ALOAD(0);
  CFENCE;
  BSTAGE(0);
  BSTAGE(1);
  CFENCE;

  STEP(0, 2);   STEP(1, 2);   STEP(2, 2);   STEP(3, 2);
  STEP(4, 2);   STEP(5, 2);   STEP(6, 2);   STEP(7, 2);
  STEP(8, 2);   STEP(9, 2);   STEP(10, 2);  STEP(11, 2);
  STEP(12, 2);  STEP(13, 2);  STEP(14, 2);  STEP(15, 0);

  // ---- epilogue: d -> (o0, o1) f32x2 store ----
  const int rbase = m0 + wm * 64 + (lane >> 4) * 4;
  const bool full = (n0 + BN <= C_TOT);  // only n0=896 tile needs guarding

#pragma unroll
  for (int ni = 0; ni < 4; ++ni) {
    const int n = n0 + wn * 64 + ni * 16 + ar;   // < 1024 always
    if (full || n < C_TOT) {
      const float bd_r = bdiff[n];
#pragma unroll
      for (int mi = 0; mi < 4; ++mi) {
#pragma unroll
        for (int j = 0; j < 4; ++j) {
          const float d = acc[mi][ni][j] + bd_r;
          const float o0 = fminf(d, 0.0f) - __logf(1.0f + __expf(-fabsf(d)));
          const int row = rbase + mi * 16 + j;
          f32x2 v;
          v.x = o0;
          v.y = o0 - d;
          *(f32x2*)(out + (size_t)row * OUT_STRIDE + 2 * n) = v;
        }
      }
    }
  }
#undef ALOAD
#undef ACVT_WR
#undef BSTAGE
#undef COMPUTE
#undef STEP
}

// ---------- naive fp32 fallback (only if ws too small) ----------
__global__ __launch_bounds__(256) void naive_kernel(const float* __restrict__ x,
                                                    const float* __restrict__ W,
                                                    const float* __restrict__ b,
                                                    float* __restrict__ out) {
  __shared__ float xs[K_TOT];
  const int row = blockIdx.x;
  for (int i = threadIdx.x; i < K_TOT; i += 256) xs[i] = x[(size_t)row * K_TOT + i];
  __syncthreads();
  for (int c = threadIdx.x; c < C_TOT; c += 256) {
    const float* w0 = W + (size_t)c * 1024;
    float l0 = b[c * 2], l1 = b[c * 2 + 1];
    for (int k = 0; k < K_TOT; ++k) {
      const float xv = xs[k];
      l0 += xv * w0[k];
      l1 += xv * w0[K_TOT + k];
    }
    const float d = l0 - l1;
    const float t = __logf(1.0f + __expf(-fabsf(d)));
    out[(size_t)row * OUT_STRIDE + c * 2]     = fminf(d, 0.0f) - t;
    out[(size_t)row * OUT_STRIDE + c * 2 + 1] = fminf(-d, 0.0f) - t;
  }
}

extern "C" void kernel_launch(void* const* d_in, const int* in_sizes, int n_in,
                              void* d_out, int out_size, void* d_ws, size_t ws_size,
                              hipStream_t stream) {
  const float* x = (const float*)d_in[0];   // [16384, 512]
  const float* W = (const float*)d_in[1];   // [1000, 2, 512]
  const float* b = (const float*)d_in[2];   // [1000, 2]
  float* out = (float*)d_out;               // [16384, 1000, 2]

  const size_t nwd = (size_t)N_PAD * K_TOT;                 // 524288 elems
  const size_t need = nwd * sizeof(u16) + N_PAD * sizeof(float);

  if (ws_size < need) {
    naive_kernel<<<M_TOT, 256, 0, stream>>>(x, W, b, out);
    return;
  }

  u16* wd = (u16*)d_ws;
  float* bd = (float*)(wd + nwd);

  wprep_kernel<<<256, 256, 0, stream>>>(W, b, wd, bd);
  gemm_ls_kernel<<<NWG, 256, 0, stream>>>(x, wd, bd, out);
}